// Round 5
// baseline (227.253 us; speedup 1.0000x reference)
//
#include <hip/hip_runtime.h>

#define NF    25     // input features per row
#define NPAIR 300    // upper-triangle pairs (25*24/2)
#define NCOL  425    // output cols: 25*5 + 300
#define ROWS  8      // rows staged per block-chunk
#define BLK   256
#define LOADN (ROWS * NF)         // 200 input floats per chunk
#define TILE4 (ROWS * NCOL / 4)   // 850 float4s per chunk (13600 B)

typedef float f32x4 __attribute__((ext_vector_type(4)));

__global__ __launch_bounds__(BLK) void feat_expand_kernel(
    const float* __restrict__ x, float* __restrict__ out,
    int nrows, int nchunks) {
  __shared__ f32x4 tile4[TILE4];            // 13600 B
  __shared__ float  xs[LOADN];              // 800 B
  __shared__ unsigned short pairs[NPAIR];   // 600 B
  float* tile = (float*)tile4;

  const int tid = threadIdx.x;
  const int r200 = tid / NF;                // row within chunk (threads < 200)
  const int i200 = tid - r200 * NF;         // col within row

  // (i,j) pair table, row-major upper triangle. NPAIR > BLK: stride it.
  for (int p = tid; p < NPAIR; p += BLK) {
    int rem = p, i = 0;
    while (rem >= (NF - 1 - i)) { rem -= (NF - 1 - i); ++i; }
    pairs[p] = (unsigned short)(i | ((i + 1 + rem) << 8));
  }

  // Prologue: prefetch first chunk's inputs into a register
  float v = 0.0f;
  {
    const long long c0 = blockIdx.x;
    if (tid < LOADN && c0 < nchunks) {
      const long long rowbase = c0 * ROWS;
      if (rowbase + r200 < nrows)
        v = __builtin_nontemporal_load(&x[rowbase * NF + tid]);
    }
  }

  for (long long chunk = blockIdx.x; chunk < nchunks; chunk += gridDim.x) {
    const long long rowbase = chunk * ROWS;
    const long long rem = nrows - rowbase;
    const int rows_here = (int)(rem < ROWS ? rem : ROWS);

    __syncthreads();                 // prev iter's xs/tile readers done
    if (tid < LOADN) xs[tid] = v;
    __syncthreads();                 // xs ready

    // Prefetch next chunk (latency hidden under B+C of this chunk)
    float vnext = 0.0f;
    {
      const long long nc = chunk + gridDim.x;
      if (tid < LOADN && nc < nchunks) {
        const long long nbase = nc * ROWS;
        if (nbase + r200 < nrows)
          vnext = __builtin_nontemporal_load(&x[nbase * NF + tid]);
      }
    }

    // Phase B1: unary features from the register (no xs re-read).
    // Tail rows compute garbage from v=0 but are never stored.
    if (tid < LOADN) {
      float* tr = &tile[r200 * NCOL];
      const float ax = fabsf(v) + 1e-10f;
      const float l2 = __builtin_amdgcn_logf(ax);        // v_log_f32
      tr[i200]        = v;                               // identity
      tr[NF + i200]   = v * v;                           // square
      tr[2*NF + i200] = l2 * 0.69314718055994530942f;    // ln = log2*ln2
      tr[3*NF + i200] = sqrtf(ax);                       // v_sqrt_f32
      tr[4*NF + i200] = __builtin_amdgcn_exp2f(l2 * (1.0f/3.0f)); // cbrt
    }

    // Phase B2: 2400 pair products = 9*256 + 96, compile-time unrolled
#pragma unroll
    for (int k = 0; k < 10; ++k) {
      const int p = tid + k * BLK;
      if (k < 9 || p < ROWS * NPAIR) {
        const int r = p / NPAIR, q = p - r * NPAIR;
        const unsigned short pr = pairs[q];
        tile[r * NCOL + 5 * NF + q] =
            xs[r * NF + (pr & 0xFF)] * xs[r * NF + (pr >> 8)];
      }
    }
    __syncthreads();                 // tile ready

    // Phase C: 850 float4 nt-stores = 3*256 + 82
    if (rows_here == ROWS) {
      f32x4* __restrict__ o4 = (f32x4*)(out + rowbase * NCOL);
      __builtin_nontemporal_store(tile4[tid],            &o4[tid]);
      __builtin_nontemporal_store(tile4[tid + BLK],      &o4[tid + BLK]);
      __builtin_nontemporal_store(tile4[tid + 2 * BLK],  &o4[tid + 2 * BLK]);
      if (tid < TILE4 - 3 * BLK)
        __builtin_nontemporal_store(tile4[tid + 3 * BLK], &o4[tid + 3 * BLK]);
    } else {  // tail chunk (not hit when nrows % ROWS == 0)
      const int total = rows_here * NCOL;
      for (int o = tid; o < total; o += BLK)
        out[rowbase * NCOL + o] = tile[o];
    }

    v = vnext;
  }
}

extern "C" void kernel_launch(void* const* d_in, const int* in_sizes, int n_in,
                              void* d_out, int out_size, void* d_ws, size_t ws_size,
                              hipStream_t stream) {
  const float* x = (const float*)d_in[0];
  float* out = (float*)d_out;

  const int nrows = in_sizes[0] / NF;                 // 524288
  const int nchunks = (nrows + ROWS - 1) / ROWS;      // 65536
  // 2048 blocks = 8 resident blocks/CU * 256 CU: every block stays warm,
  // prefetch pipeline exposed only once per block.
  const int grid = nchunks < 2048 ? nchunks : 2048;

  feat_expand_kernel<<<grid, BLK, 0, stream>>>(x, out, nrows, nchunks);
}

// Round 6
// 214.699 us; speedup vs baseline: 1.0585x; 1.0585x over previous
//
#include <hip/hip_runtime.h>

#define NF     25                 // input features per row
#define NPAIR  300                // upper-triangle pairs
#define NUNARY 125                // unary outputs per row (5*25)
#define NCOL   425                // output cols per row
#define ROWS   8                  // rows per chunk
#define BLK    256
#define TILE_DW (ROWS * NCOL)     // 3400 dwords per chunk
#define TILE4   (TILE_DW / 4)     // 850 float4s (13600 B, 16B-aligned)
#define VALS_N  (ROWS * NF + ROWS * NUNARY + 4)  // 200 xs + 1000 unary + pad

typedef float f32x4 __attribute__((ext_vector_type(4)));
typedef unsigned int u32;
typedef u32 u32x4 __attribute__((ext_vector_type(4)));

#define ONE_SLOT (ROWS * NF + ROWS * NUNARY)     // vals[1200] == 1.0f

__global__ __launch_bounds__(BLK) void feat_expand_kernel(
    const float* __restrict__ x, float* __restrict__ out,
    int nrows, int nchunks) {
  // vals layout: [0,200) staged x | [200,1200) unary features | [1200] = 1.0f
  __shared__ float vals[VALS_N];            // 4816 B
  __shared__ u32x4 dtab4[TILE4];            // 13600 B: desc per output dword
  u32* dtab = (u32*)dtab4;

  const int tid = threadIdx.x;
  const int r200 = tid / NF;                // row within chunk (threads < 200)
  const int i200 = tid - r200 * NF;

  // ---- One-time per block: descriptor table + the 1.0 slot ----
  // desc = offA | (offB << 16); out_dword(o) = vals[offA] * vals[offB]
  if (tid == 0) vals[ONE_SLOT] = 1.0f;
  for (int o = tid; o < TILE_DW; o += BLK) {
    const int r = o / NCOL, c = o - r * NCOL;
    u32 d;
    if (c < NUNARY) {
      d = (u32)(ROWS * NF + r * NUNARY + c) | ((u32)ONE_SLOT << 16);
    } else {
      int rem = c - NUNARY, i = 0;
      while (rem >= (NF - 1 - i)) { rem -= (NF - 1 - i); ++i; }
      const int j = i + 1 + rem;
      d = (u32)(r * NF + i) | ((u32)(r * NF + j) << 16);
    }
    dtab[o] = d;
  }

  for (int chunk = blockIdx.x; chunk < nchunks; chunk += gridDim.x) {
    const long long rowbase = (long long)chunk * ROWS;
    const long long remrows = nrows - rowbase;
    const int rows_here = (int)(remrows < ROWS ? remrows : ROWS);

    __syncthreads();  // prev iter's vals readers done (also fences dtab, iter 0)

    // Phase A+B: stage x and compute unary features (200 threads, no divergence)
    if (tid < ROWS * NF && r200 < rows_here) {
      const float v = x[rowbase * NF + tid];
      vals[tid] = v;
      float* ur = &vals[ROWS * NF + r200 * NUNARY];
      const float ax = fabsf(v) + 1e-10f;
      const float l2 = __builtin_amdgcn_logf(ax);        // v_log_f32: log2
      ur[i200]          = v;                             // identity
      ur[NF + i200]     = v * v;                         // square
      ur[2*NF + i200]   = l2 * 0.69314718055994530942f;  // ln = log2*ln2
      ur[3*NF + i200]   = sqrtf(ax);                     // v_sqrt_f32
      ur[4*NF + i200]   = __builtin_amdgcn_exp2f(l2 * (1.0f/3.0f)); // cbrt
    }
    __syncthreads();  // vals ready

    // Phase C: assemble float4s in registers from desc table, nt-store.
    if (rows_here == ROWS) {
      f32x4* __restrict__ o4 = (f32x4*)(out + rowbase * NCOL);
#pragma unroll
      for (int k = 0; k < 4; ++k) {
        const int v4 = tid + k * BLK;        // 850 = 3*256 + 82
        if (k < 3 || v4 < TILE4) {
          const u32x4 d = dtab4[v4];
          f32x4 ov;
          ov.x = vals[d.x & 0xFFFF] * vals[d.x >> 16];
          ov.y = vals[d.y & 0xFFFF] * vals[d.y >> 16];
          ov.z = vals[d.z & 0xFFFF] * vals[d.z >> 16];
          ov.w = vals[d.w & 0xFFFF] * vals[d.w >> 16];
          __builtin_nontemporal_store(ov, &o4[v4]);
        }
      }
    } else {  // tail chunk (not hit when nrows % ROWS == 0) — scalar
      const int total = rows_here * NCOL;
      for (int o = tid; o < total; o += BLK) {
        const u32 d = dtab[o];
        out[rowbase * NCOL + o] = vals[d & 0xFFFF] * vals[d >> 16];
      }
    }
  }
}

extern "C" void kernel_launch(void* const* d_in, const int* in_sizes, int n_in,
                              void* d_out, int out_size, void* d_ws, size_t ws_size,
                              hipStream_t stream) {
  const float* x = (const float*)d_in[0];
  float* out = (float*)d_out;

  const int nrows = in_sizes[0] / NF;                 // 524288
  const int nchunks = (nrows + ROWS - 1) / ROWS;      // 65536
  const int grid = nchunks < 4096 ? nchunks : 4096;   // round-4 known-good

  feat_expand_kernel<<<grid, BLK, 0, stream>>>(x, out, nrows, nchunks);
}